// Round 7
// baseline (144.356 us; speedup 1.0000x reference)
//
#include <hip/hip_runtime.h>

// ---------------------------------------------------------------------------
// GeometricSuperpositionSearch (all fp32): the reference collapses to
//   new[b,n,l] = sum_j x[b,n,j] * comb[b][j^l] * sign(j^l, j)
// where comb[b] is a single 16-component multivector per batch:
//   comb[b][i] = sum_k weights[b,k] * scores[b,k] * (templates[k,i] + rule_mod[b,k,i])
//
// R11: single-WAVE k2 fused into k3 (fixing R10's 8x-overweight version).
//  R10 post-mortem: per-block k2 = 4.5us (12 barrier phases, all 8 batches,
//  64KB partial re-read) -> k3_fused 46us. But FETCH=16.8MB proved k3's cpu
//  re-read is ~50% L3-hit, so fusion upside is real if k2b is ~1us.
//  Fix: each block computes ONLY its batch's comb[16] in wave 0,
//  wave-synchronously (zero __syncthreads, all cross-lane via __shfl):
//   partial[b] (8KB, 32 coalesced loads/lane) -> xor-reduce -> grade norms
//   -> 64-lane MLP -> shuffle-reduced scores -> per-lane threefry gumbel
//   -> replicated softmax -> pair-decomposed comb reduction.
//  Overlaps with the block's 16KB tile loads (issued first, in flight).
//  LDS = tile 16K + comb 64B (no K2Shared -> R10's 1.1M bank conflicts gone).
//  Graph = 2 kernels: k1 reduce -> k3_fused2.
//  Cooperative sync: permanently abandoned (R6 300us / R8 225us).
// RNG: jax partitionable threefry: counter (0, b*8+k), key (0, 42),
// bits = x0 ^ x1.  (Verified: absmax 3.9e-3.)
// ---------------------------------------------------------------------------

#define B_ 8
#define N_ 65536
#define D_ 16
#define K_ 8
#define M_ 8
#define HID_ 64
#define BLK_PER_B 128                    // k1 slabs per batch
#define ROWS_PER_BLK (N_ / BLK_PER_B)    // 512 rows -> 2048 float4 per slab

typedef float f4v __attribute__((ext_vector_type(4)));

// ---- compile-time Cayley sign table: SGN.v[a][b] = sign of e_a * e_b -> e_{a^b}
struct SgnTab { float v[16][16]; };
constexpr SgnTab make_sgn() {
  SgnTab t{};
  for (int a = 0; a < 16; a++)
    for (int b = 0; b < 16; b++) {
      float s = 1.0f;
      for (int i = 0; i < 4; i++)
        if ((b >> i) & 1) {
          int h = a >> (i + 1), pc = 0;
          for (int q = 0; q < 4; q++) pc += (h >> q) & 1;
          if (pc & 1) s = -s;
          if ((a >> i) & 1) s *= (i == 0 ? 0.0f : 1.0f);  // metric {0,1,1,1}
        }
      t.v[a][b] = s;
    }
  return t;
}
constexpr SgnTab SGN = make_sgn();

// ---- threefry2x32-20, exactly as in jax/_src/prng.py ----
__device__ __forceinline__ unsigned rotl32(unsigned x, int n) {
  return (x << n) | (x >> (32 - n));
}
__device__ void threefry2x32(unsigned k0, unsigned k1, unsigned& x0, unsigned& x1) {
  unsigned ks0 = k0, ks1 = k1, ks2 = k0 ^ k1 ^ 0x1BD11BDAu;
  x0 += ks0; x1 += ks1;
  const int rotA[4] = {13, 15, 26, 6};
  const int rotB[4] = {17, 29, 16, 24};
#define TF_R4(rot)                                      \
  _Pragma("unroll")                                     \
  for (int r = 0; r < 4; r++) {                         \
    x0 += x1; x1 = rotl32(x1, rot[r]); x1 ^= x0;        \
  }
  TF_R4(rotA); x0 += ks1; x1 += ks2 + 1u;
  TF_R4(rotB); x0 += ks2; x1 += ks0 + 2u;
  TF_R4(rotA); x0 += ks0; x1 += ks1 + 3u;
  TF_R4(rotB); x0 += ks1; x1 += ks2 + 4u;
  TF_R4(rotA); x0 += ks2; x1 += ks0 + 5u;
#undef TF_R4
}

__device__ __forceinline__ void apply_row(const float cb[16], const float x[16],
                                          float o[16]) {
#pragma unroll
  for (int l = 0; l < 16; l++) {
    float acc = 0.f;
#pragma unroll
    for (int j = 0; j < 16; j++) {
      const float s = SGN.v[j ^ l][j];                  // compile-time constant
      if (s > 0.5f)       acc = fmaf(cb[j ^ l], x[j], acc);
      else if (s < -0.5f) acc = fmaf(-cb[j ^ l], x[j], acc);
    }
    o[l] = acc;
  }
}

// ---------------------------------------------------------------------------
// k2b_wave: ONE wave computes comb[b][16] wave-synchronously (no barriers).
// lane = t (0..63). All reductions via __shfl/__shfl_xor (width 64).
// ---------------------------------------------------------------------------
__device__ void k2b_wave(int lane, int b,
                         const float* __restrict__ partial,   // [8][128][16]
                         const float* __restrict__ ctrl,
                         const float* __restrict__ rulemem,
                         const float* __restrict__ templates,
                         const float* __restrict__ W1,
                         const float* __restrict__ b1,
                         const float* __restrict__ W2,
                         const float* __restrict__ b2,
                         const float* __restrict__ Wr,
                         const float* __restrict__ br,
                         const float* __restrict__ logt,
                         float* __restrict__ comb_lds) {      // [16]
  // 1. summary[d]: partial[b] = 2048 floats; lane sums stride-64 columns.
  //    idx = c*64+lane -> d = lane&15 (64 == 0 mod 16), covers all 128 slabs.
  const float* pb = partial + b * 2048;
  float acc = 0.f;
#pragma unroll
  for (int c = 0; c < 32; c++) acc += pb[c * 64 + lane];
  acc += __shfl_xor(acc, 16);
  acc += __shfl_xor(acc, 32);
  const float summary = acc * (1.0f / (float)N_);   // for d = lane&15

  // 2. grade norms gn[5] (replicated per lane)
  float gn[5];
  {
    const float sq = summary * summary;
    float s[5] = {0.f, 0.f, 0.f, 0.f, 0.f};
#pragma unroll
    for (int d = 0; d < 16; d++) s[__popc(d)] += __shfl(sq, d);  // popc const-folds
#pragma unroll
    for (int g = 0; g < 5; g++) gn[g] = sqrtf(s[g] + 1e-12f);
  }

  // 3. hidden layer: h[j=lane] = relu(b1 + [gn,ctrl] . W1[:,lane])
  float h;
  {
    float a = b1[lane];
#pragma unroll
    for (int i = 0; i < 5; i++) a += gn[i] * W1[i * HID_ + lane];
#pragma unroll
    for (int i = 0; i < 4; i++) a += ctrl[b * 4 + i] * W1[(5 + i) * HID_ + lane];
    h = fmaxf(a, 0.f);
  }

  // 4. scores sc[8] (full-wave dot per k, replicated everywhere)
  float sc[8];
#pragma unroll
  for (int k = 0; k < 8; k++) {
    float v = h * W2[lane * K_ + k];
#pragma unroll
    for (int off = 1; off < 64; off <<= 1) v += __shfl_xor(v, off);
    sc[k] = v + b2[k];
  }

  // 5. gumbel for k = lane&7: counter (0, b*8+k), key (0, 42)
  float gk;
  {
    unsigned x0 = 0u, x1 = (unsigned)(b * 8 + (lane & 7));
    threefry2x32(0u, 42u, x0, x1);
    unsigned bits = x0 ^ x1;
    float f01 = __uint_as_float((bits >> 9) | 0x3f800000u) - 1.0f;
    float u = fmaxf(1e-6f, f01 * (1.0f - 2e-6f) + 1e-6f);
    gk = -logf(-logf(u));
  }

  // softmax -> wsc[k] = weights[k]*scores[k] (replicated per lane)
  float wsc[8];
  {
    float lt = logt[0];
    float tau = fminf(fmaxf(expf(lt), 0.1f), 5.0f);
    float z[8], m = -1e30f;
#pragma unroll
    for (int k = 0; k < 8; k++) {
      z[k] = (sc[k] + __shfl(gk, k)) / tau;
      m = fmaxf(m, z[k]);
    }
    float ssum = 0.f;
#pragma unroll
    for (int k = 0; k < 8; k++) { z[k] = expf(z[k] - m); ssum += z[k]; }
#pragma unroll
    for (int k = 0; k < 8; k++) wsc[k] = (z[k] / ssum) * sc[k];
  }

  // 6. rule summary rs[16], distributed to all lanes
  float rs_all[16];
  {
    float rs_own = 0.f;
#pragma unroll
    for (int m = 0; m < M_; m++) rs_own += rulemem[(b * M_ + m) * 16 + (lane & 15)];
    rs_own *= (1.0f / (float)M_);
#pragma unroll
    for (int j = 0; j < 16; j++) rs_all[j] = __shfl(rs_own, j);
  }

  // 7. comb[i] via pair decomposition: pairs p = lane, lane+64
  //    (k = p>>4, i = p&15; note k*16+i == p), then xor-reduce over k.
  float c = 0.f;
#pragma unroll
  for (int pp = 0; pp < 2; pp++) {
    const int p = lane + pp * 64;
    float val = templates[p] + br[p];
#pragma unroll
    for (int j = 0; j < 16; j++) val += rs_all[j] * Wr[j * 128 + p];
    c += wsc[p >> 4] * val;
  }
  c += __shfl_xor(c, 16);     // k ^ 1
  c += __shfl_xor(c, 32);     // k ^ 2  -> all 8 k summed; i = lane&15
  if (lane < 16) comb_lds[lane] = c;
}

// ---------------------------------------------------------------------------
// k1: per-(b,d) partial sums of cpu_state over a 512-row slab.
// grid (BLK_PER_B, B_) = 1024 blocks, 256 threads. Fully coalesced loads.
// ---------------------------------------------------------------------------
__global__ __launch_bounds__(256) void k1_reduce(
    const float* __restrict__ cpu, float* __restrict__ partial) {
  const int b = blockIdx.y, blk = blockIdx.x, t = threadIdx.x;
  const float4* base =
      (const float4*)(cpu + (((size_t)b << 16) + (size_t)blk * ROWS_PER_BLK) * D_);
  float a0 = 0.f, a1 = 0.f, a2 = 0.f, a3 = 0.f;
#pragma unroll
  for (int i = 0; i < (ROWS_PER_BLK * 4) / 256; i++) {   // 8 iters
    float4 v = base[i * 256 + t];
    a0 += v.x; a1 += v.y; a2 += v.z; a3 += v.w;
  }
  __shared__ float red[256 * 4];
  red[t * 4 + 0] = a0; red[t * 4 + 1] = a1;
  red[t * 4 + 2] = a2; red[t * 4 + 3] = a3;
  __syncthreads();
  if (t < 16) {
    const int c = t >> 2, j = t & 3;      // component d = 4c + j = t
    float s = 0.f;
#pragma unroll
    for (int m = 0; m < 64; m++) s += red[(c + 4 * m) * 4 + j];
    partial[((size_t)b * BLK_PER_B + blk) * 16 + t] = s;
  }
}

// ---------------------------------------------------------------------------
// k3_fused2 (R11): wave-level k2b + R9's coalesced apply, one kernel.
// grid 2048 blocks x 256 threads; each block owns a 256-row tile.
//   0. issue tile loads (4 float4/thread) into registers        (in flight)
//   1. wave 0: k2b_wave -> comb_lds[16]  (ONLY this block's batch)
//      waves 1-3: nothing (their tile regs in flight)
//   2. all: tile regs -> swizzled LDS; __syncthreads (comb + tile ready)
//   3. per-thread row from LDS (b128 bank floor), apply_row, write back
//   4. coalesced nontemporal stores
// swizzle: slot(r,w) = r*4 + (w ^ (r&3) ^ ((r>>2)&3))  (bijective per quad)
// ---------------------------------------------------------------------------
__global__ __launch_bounds__(256) void k3_fused2(
    const float* __restrict__ cpu,
    const float* __restrict__ partial,
    const float* __restrict__ ctrl,
    const float* __restrict__ rulemem,
    const float* __restrict__ templates,
    const float* __restrict__ W1, const float* __restrict__ b1,
    const float* __restrict__ W2, const float* __restrict__ b2,
    const float* __restrict__ Wr, const float* __restrict__ br,
    const float* __restrict__ logt,
    float* __restrict__ out) {
  const int t = threadIdx.x;
  const int b = blockIdx.x >> 8;                    // 256 blocks per batch
  const size_t base4 = (size_t)blockIdx.x * 1024;   // float4 idx of tile start

  __shared__ float4 lds4[1024];                     // 16 KB tile
  __shared__ float comb_lds[16];

  const float4* in4 = (const float4*)cpu + base4;
  float4* out4 = (float4*)out + base4;

  // 0. issue tile loads into registers (overlap wave-0's k2b chain)
  float4 r0 = in4[0 * 256 + t];
  float4 r1 = in4[1 * 256 + t];
  float4 r2 = in4[2 * 256 + t];
  float4 r3 = in4[3 * 256 + t];

  // 1. wave 0 computes this batch's comb (wave-synchronous, no barriers)
  if (t < 64)
    k2b_wave(t, b, partial, ctrl, rulemem, templates, W1, b1, W2, b2, Wr, br,
             logt, comb_lds);

  // 2. stage tile into swizzled LDS
  const int sw = ((t >> 2) & 3) ^ ((t >> 4) & 3);   // linear-phase swizzle
  lds4[(0 * 256 + t) ^ sw] = r0;
  lds4[(1 * 256 + t) ^ sw] = r1;
  lds4[(2 * 256 + t) ^ sw] = r2;
  lds4[(3 * 256 + t) ^ sw] = r3;
  __syncthreads();                                  // comb + tile both ready

  float cb[16];
#pragma unroll
  for (int i = 0; i < 16; i++) cb[i] = comb_lds[i];

  // 3. own row t from LDS, compute, write back in place (rows disjoint)
  {
    const int rsw = (t & 3) ^ ((t >> 2) & 3);
    float4 q0 = lds4[t * 4 + (0 ^ rsw)];
    float4 q1 = lds4[t * 4 + (1 ^ rsw)];
    float4 q2 = lds4[t * 4 + (2 ^ rsw)];
    float4 q3 = lds4[t * 4 + (3 ^ rsw)];
    float x[16] = {q0.x, q0.y, q0.z, q0.w, q1.x, q1.y, q1.z, q1.w,
                   q2.x, q2.y, q2.z, q2.w, q3.x, q3.y, q3.z, q3.w};
    float o[16];
    apply_row(cb, x, o);
    lds4[t * 4 + (0 ^ rsw)] = make_float4(o[0],  o[1],  o[2],  o[3]);
    lds4[t * 4 + (1 ^ rsw)] = make_float4(o[4],  o[5],  o[6],  o[7]);
    lds4[t * 4 + (2 ^ rsw)] = make_float4(o[8],  o[9],  o[10], o[11]);
    lds4[t * 4 + (3 ^ rsw)] = make_float4(o[12], o[13], o[14], o[15]);
  }
  __syncthreads();

  // 4. swizzled LDS -> coalesced nontemporal store (out is never re-read)
#pragma unroll
  for (int i = 0; i < 4; i++) {
    const int m = i * 256 + t;
    f4v v = *(const f4v*)&lds4[m ^ sw];
    __builtin_nontemporal_store(v, (f4v*)&out4[m]);
  }
}

// ---------------------------------------------------------------------------
// Fallback (tiny-workspace) path: R9's verified 3-kernel structure.
// ---------------------------------------------------------------------------
__global__ __launch_bounds__(256) void k2_wave_only(
    const float* __restrict__ partial, const float* __restrict__ ctrl,
    const float* __restrict__ rulemem, const float* __restrict__ templates,
    const float* __restrict__ W1, const float* __restrict__ b1,
    const float* __restrict__ W2, const float* __restrict__ b2,
    const float* __restrict__ Wr, const float* __restrict__ br,
    const float* __restrict__ logt, float* __restrict__ comb) {
  // 8 blocks, one wave each: block b -> comb[b*16..]
  __shared__ float comb_lds[16];
  const int t = threadIdx.x;
  if (t < 64)
    k2b_wave(t, blockIdx.x, partial, ctrl, rulemem, templates, W1, b1, W2, b2,
             Wr, br, logt, comb_lds);
  __syncthreads();
  if (t < 16) comb[blockIdx.x * 16 + t] = comb_lds[t];
}

__global__ __launch_bounds__(256) void k3_apply_g(
    const float* __restrict__ cpu, const float* __restrict__ comb,
    float* __restrict__ out) {
  const int t = threadIdx.x;
  const int b = blockIdx.x >> 8;
  const size_t base4 = (size_t)blockIdx.x * 1024;
  __shared__ float4 lds4[1024];

  float cb[16];
  {
    const float* cp = comb + b * 16;
#pragma unroll
    for (int i = 0; i < 16; i++) cb[i] = cp[i];
  }
  const float4* in4 = (const float4*)cpu + base4;
  float4* out4 = (float4*)out + base4;
  const int sw = ((t >> 2) & 3) ^ ((t >> 4) & 3);
#pragma unroll
  for (int i = 0; i < 4; i++) {
    const int m = i * 256 + t;
    lds4[m ^ sw] = in4[m];
  }
  __syncthreads();
  {
    const int rsw = (t & 3) ^ ((t >> 2) & 3);
    float4 q0 = lds4[t * 4 + (0 ^ rsw)];
    float4 q1 = lds4[t * 4 + (1 ^ rsw)];
    float4 q2 = lds4[t * 4 + (2 ^ rsw)];
    float4 q3 = lds4[t * 4 + (3 ^ rsw)];
    float x[16] = {q0.x, q0.y, q0.z, q0.w, q1.x, q1.y, q1.z, q1.w,
                   q2.x, q2.y, q2.z, q2.w, q3.x, q3.y, q3.z, q3.w};
    float o[16];
    apply_row(cb, x, o);
    lds4[t * 4 + (0 ^ rsw)] = make_float4(o[0],  o[1],  o[2],  o[3]);
    lds4[t * 4 + (1 ^ rsw)] = make_float4(o[4],  o[5],  o[6],  o[7]);
    lds4[t * 4 + (2 ^ rsw)] = make_float4(o[8],  o[9],  o[10], o[11]);
    lds4[t * 4 + (3 ^ rsw)] = make_float4(o[12], o[13], o[14], o[15]);
  }
  __syncthreads();
#pragma unroll
  for (int i = 0; i < 4; i++) {
    const int m = i * 256 + t;
    f4v v = *(const f4v*)&lds4[m ^ sw];
    __builtin_nontemporal_store(v, (f4v*)&out4[m]);
  }
}

extern "C" void kernel_launch(void* const* d_in, const int* in_sizes, int n_in,
                              void* d_out, int out_size, void* d_ws, size_t ws_size,
                              hipStream_t stream) {
  const float* cpu       = (const float*)d_in[0];
  const float* ctrl      = (const float*)d_in[1];
  const float* rulemem   = (const float*)d_in[2];
  const float* templates = (const float*)d_in[3];
  const float* W1        = (const float*)d_in[4];
  const float* b1        = (const float*)d_in[5];
  const float* W2        = (const float*)d_in[6];
  const float* b2        = (const float*)d_in[7];
  const float* Wr        = (const float*)d_in[8];
  const float* br        = (const float*)d_in[9];
  const float* logt      = (const float*)d_in[10];
  float* outp = (float*)d_out;

  float* partial = (float*)d_ws;                       // 8*128*16 floats
  const size_t need = (size_t)(B_ * BLK_PER_B * 16) * sizeof(float);

  if (ws_size >= need) {
    // R11 2-kernel path: k1 reduce -> k3 fused (wave-level per-batch k2)
    k1_reduce<<<dim3(BLK_PER_B, B_), 256, 0, stream>>>(cpu, partial);
    k3_fused2<<<2048, 256, 0, stream>>>(cpu, partial, ctrl, rulemem, templates,
                                        W1, b1, W2, b2, Wr, br, logt, outp);
  } else {
    // tiny-ws fallback: 3-kernel path (partial staged in out, fully consumed
    // by k2 before k3's first store; comb in ws)
    float* comb = (float*)d_ws;
    partial = outp;
    k1_reduce<<<dim3(BLK_PER_B, B_), 256, 0, stream>>>(cpu, partial);
    k2_wave_only<<<8, 256, 0, stream>>>(partial, ctrl, rulemem, templates, W1,
                                        b1, W2, b2, Wr, br, logt, comb);
    k3_apply_g<<<2048, 256, 0, stream>>>(cpu, comb, outp);
  }
}

// Round 8
// 109.475 us; speedup vs baseline: 1.3186x; 1.3186x over previous
//
#include <hip/hip_runtime.h>

// ---------------------------------------------------------------------------
// GeometricSuperpositionSearch (all fp32): the reference collapses to
//   new[b,n,l] = sum_j x[b,n,j] * comb[b][j^l] * sign(j^l, j)
// where comb[b] is a single 16-component multivector per batch:
//   comb[b][i] = sum_k weights[b,k] * scores[b,k] * (templates[k,i] + rule_mod[b,k,i])
//
// R12: revert to the 3-dispatch graph (best measured: R9 @113.0us).
// Fusion post-mortems (R6 coop 300us, R8 coop-LDS 225us, R10 block-k2 46us,
// R11 wave-k2 55us): ANY serial work replicated on 2048 blocks' critical
// path loses more than the ~2us dispatch boundary it saves. Keep k2 as its
// own tiny dispatch, run ONCE.
// This round:
//  a) k2 = 8 blocks x 1 wave (k2b_wave, HW-verified in R11) instead of the
//     12-barrier single-block version: 4.5us -> ~2us.
//  b) k3 XCD-matched tile remap: k1 slab s of batch b runs on XCD s%8
//     (linear id s+128b, 128==0 mod 8). Map k3 block g -> tile with
//     tile/2 % 8 == g%8 so its re-read hits the same XCD's L2 that k1
//     filled (R10/R11 FETCH showed only ~50% absorption without this).
//     Bijective: g=(x,r): b=r>>5, m=(r&31)>>1, o=r&1, tile=2*(x+8m)+o.
// RNG: jax partitionable threefry: counter (0, b*8+k), key (0, 42),
// bits = x0 ^ x1.  (Verified: absmax 3.9e-3.)
// ---------------------------------------------------------------------------

#define B_ 8
#define N_ 65536
#define D_ 16
#define K_ 8
#define M_ 8
#define HID_ 64
#define BLK_PER_B 128                    // k1 slabs per batch
#define ROWS_PER_BLK (N_ / BLK_PER_B)    // 512 rows -> 2048 float4 per slab

typedef float f4v __attribute__((ext_vector_type(4)));

// ---- compile-time Cayley sign table: SGN.v[a][b] = sign of e_a * e_b -> e_{a^b}
struct SgnTab { float v[16][16]; };
constexpr SgnTab make_sgn() {
  SgnTab t{};
  for (int a = 0; a < 16; a++)
    for (int b = 0; b < 16; b++) {
      float s = 1.0f;
      for (int i = 0; i < 4; i++)
        if ((b >> i) & 1) {
          int h = a >> (i + 1), pc = 0;
          for (int q = 0; q < 4; q++) pc += (h >> q) & 1;
          if (pc & 1) s = -s;
          if ((a >> i) & 1) s *= (i == 0 ? 0.0f : 1.0f);  // metric {0,1,1,1}
        }
      t.v[a][b] = s;
    }
  return t;
}
constexpr SgnTab SGN = make_sgn();

// ---- threefry2x32-20, exactly as in jax/_src/prng.py ----
__device__ __forceinline__ unsigned rotl32(unsigned x, int n) {
  return (x << n) | (x >> (32 - n));
}
__device__ void threefry2x32(unsigned k0, unsigned k1, unsigned& x0, unsigned& x1) {
  unsigned ks0 = k0, ks1 = k1, ks2 = k0 ^ k1 ^ 0x1BD11BDAu;
  x0 += ks0; x1 += ks1;
  const int rotA[4] = {13, 15, 26, 6};
  const int rotB[4] = {17, 29, 16, 24};
#define TF_R4(rot)                                      \
  _Pragma("unroll")                                     \
  for (int r = 0; r < 4; r++) {                         \
    x0 += x1; x1 = rotl32(x1, rot[r]); x1 ^= x0;        \
  }
  TF_R4(rotA); x0 += ks1; x1 += ks2 + 1u;
  TF_R4(rotB); x0 += ks2; x1 += ks0 + 2u;
  TF_R4(rotA); x0 += ks0; x1 += ks1 + 3u;
  TF_R4(rotB); x0 += ks1; x1 += ks2 + 4u;
  TF_R4(rotA); x0 += ks2; x1 += ks0 + 5u;
#undef TF_R4
}

__device__ __forceinline__ void apply_row(const float cb[16], const float x[16],
                                          float o[16]) {
#pragma unroll
  for (int l = 0; l < 16; l++) {
    float acc = 0.f;
#pragma unroll
    for (int j = 0; j < 16; j++) {
      const float s = SGN.v[j ^ l][j];                  // compile-time constant
      if (s > 0.5f)       acc = fmaf(cb[j ^ l], x[j], acc);
      else if (s < -0.5f) acc = fmaf(-cb[j ^ l], x[j], acc);
    }
    o[l] = acc;
  }
}

// ---------------------------------------------------------------------------
// k2b_wave: ONE wave computes comb[b][16] wave-synchronously (no barriers).
// lane = t (0..63). All reductions via __shfl/__shfl_xor (width 64).
// HW-verified correct in R11 (absmax 3.9e-3 inside k3_fused2).
// ---------------------------------------------------------------------------
__device__ void k2b_wave(int lane, int b,
                         const float* __restrict__ partial,   // [8][128][16]
                         const float* __restrict__ ctrl,
                         const float* __restrict__ rulemem,
                         const float* __restrict__ templates,
                         const float* __restrict__ W1,
                         const float* __restrict__ b1,
                         const float* __restrict__ W2,
                         const float* __restrict__ b2,
                         const float* __restrict__ Wr,
                         const float* __restrict__ br,
                         const float* __restrict__ logt,
                         float* __restrict__ comb_out) {      // [16]
  // 1. summary[d]: partial[b] = 2048 floats; lane sums stride-64 columns.
  //    idx = c*64+lane -> d = lane&15 (64 == 0 mod 16), covers all 128 slabs.
  const float* pb = partial + b * 2048;
  float acc = 0.f;
#pragma unroll
  for (int c = 0; c < 32; c++) acc += pb[c * 64 + lane];
  acc += __shfl_xor(acc, 16);
  acc += __shfl_xor(acc, 32);
  const float summary = acc * (1.0f / (float)N_);   // for d = lane&15

  // 2. grade norms gn[5] (replicated per lane)
  float gn[5];
  {
    const float sq = summary * summary;
    float s[5] = {0.f, 0.f, 0.f, 0.f, 0.f};
#pragma unroll
    for (int d = 0; d < 16; d++) s[__popc(d)] += __shfl(sq, d);  // popc const-folds
#pragma unroll
    for (int g = 0; g < 5; g++) gn[g] = sqrtf(s[g] + 1e-12f);
  }

  // 3. hidden layer: h[j=lane] = relu(b1 + [gn,ctrl] . W1[:,lane])
  float h;
  {
    float a = b1[lane];
#pragma unroll
    for (int i = 0; i < 5; i++) a += gn[i] * W1[i * HID_ + lane];
#pragma unroll
    for (int i = 0; i < 4; i++) a += ctrl[b * 4 + i] * W1[(5 + i) * HID_ + lane];
    h = fmaxf(a, 0.f);
  }

  // 4. scores sc[8] (full-wave dot per k, replicated everywhere)
  float sc[8];
#pragma unroll
  for (int k = 0; k < 8; k++) {
    float v = h * W2[lane * K_ + k];
#pragma unroll
    for (int off = 1; off < 64; off <<= 1) v += __shfl_xor(v, off);
    sc[k] = v + b2[k];
  }

  // 5. gumbel for k = lane&7: counter (0, b*8+k), key (0, 42)
  float gk;
  {
    unsigned x0 = 0u, x1 = (unsigned)(b * 8 + (lane & 7));
    threefry2x32(0u, 42u, x0, x1);
    unsigned bits = x0 ^ x1;
    float f01 = __uint_as_float((bits >> 9) | 0x3f800000u) - 1.0f;
    float u = fmaxf(1e-6f, f01 * (1.0f - 2e-6f) + 1e-6f);
    gk = -logf(-logf(u));
  }

  // softmax -> wsc[k] = weights[k]*scores[k] (replicated per lane)
  float wsc[8];
  {
    float lt = logt[0];
    float tau = fminf(fmaxf(expf(lt), 0.1f), 5.0f);
    float z[8], m = -1e30f;
#pragma unroll
    for (int k = 0; k < 8; k++) {
      z[k] = (sc[k] + __shfl(gk, k)) / tau;
      m = fmaxf(m, z[k]);
    }
    float ssum = 0.f;
#pragma unroll
    for (int k = 0; k < 8; k++) { z[k] = expf(z[k] - m); ssum += z[k]; }
#pragma unroll
    for (int k = 0; k < 8; k++) wsc[k] = (z[k] / ssum) * sc[k];
  }

  // 6. rule summary rs[16], distributed to all lanes
  float rs_all[16];
  {
    float rs_own = 0.f;
#pragma unroll
    for (int m = 0; m < M_; m++) rs_own += rulemem[(b * M_ + m) * 16 + (lane & 15)];
    rs_own *= (1.0f / (float)M_);
#pragma unroll
    for (int j = 0; j < 16; j++) rs_all[j] = __shfl(rs_own, j);
  }

  // 7. comb[i] via pair decomposition: pairs p = lane, lane+64
  //    (k = p>>4, i = p&15; note k*16+i == p), then xor-reduce over k.
  float c = 0.f;
#pragma unroll
  for (int pp = 0; pp < 2; pp++) {
    const int p = lane + pp * 64;
    float val = templates[p] + br[p];
#pragma unroll
    for (int j = 0; j < 16; j++) val += rs_all[j] * Wr[j * 128 + p];
    c += wsc[p >> 4] * val;
  }
  c += __shfl_xor(c, 16);     // k ^ 1
  c += __shfl_xor(c, 32);     // k ^ 2  -> all 8 k summed; i = lane&15
  if (lane < 16) comb_out[lane] = c;
}

// ---------------------------------------------------------------------------
// k1: per-(b,d) partial sums of cpu_state over a 512-row slab.
// grid (BLK_PER_B, B_) = 1024 blocks, 256 threads. Fully coalesced loads.
// linear id = blk + 128*b -> XCD = blk % 8 (128 == 0 mod 8).
// ---------------------------------------------------------------------------
__global__ __launch_bounds__(256) void k1_reduce(
    const float* __restrict__ cpu, float* __restrict__ partial) {
  const int b = blockIdx.y, blk = blockIdx.x, t = threadIdx.x;
  const float4* base =
      (const float4*)(cpu + (((size_t)b << 16) + (size_t)blk * ROWS_PER_BLK) * D_);
  float a0 = 0.f, a1 = 0.f, a2 = 0.f, a3 = 0.f;
#pragma unroll
  for (int i = 0; i < (ROWS_PER_BLK * 4) / 256; i++) {   // 8 iters
    float4 v = base[i * 256 + t];
    a0 += v.x; a1 += v.y; a2 += v.z; a3 += v.w;
  }
  __shared__ float red[256 * 4];
  red[t * 4 + 0] = a0; red[t * 4 + 1] = a1;
  red[t * 4 + 2] = a2; red[t * 4 + 3] = a3;
  __syncthreads();
  if (t < 16) {
    const int c = t >> 2, j = t & 3;      // component d = 4c + j = t
    float s = 0.f;
#pragma unroll
    for (int m = 0; m < 64; m++) s += red[(c + 4 * m) * 4 + j];
    partial[((size_t)b * BLK_PER_B + blk) * 16 + t] = s;
  }
}

// ---------------------------------------------------------------------------
// k2: 8 blocks x 1 wave (64 threads), barrier-free -> comb[8][16]
// ---------------------------------------------------------------------------
__global__ __launch_bounds__(64) void k2_wave(
    const float* __restrict__ partial, const float* __restrict__ ctrl,
    const float* __restrict__ rulemem, const float* __restrict__ templates,
    const float* __restrict__ W1, const float* __restrict__ b1,
    const float* __restrict__ W2, const float* __restrict__ b2,
    const float* __restrict__ Wr, const float* __restrict__ br,
    const float* __restrict__ logt, float* __restrict__ comb) {
  k2b_wave(threadIdx.x, blockIdx.x, partial, ctrl, rulemem, templates, W1, b1,
           W2, b2, Wr, br, logt, comb + blockIdx.x * 16);
}

// ---------------------------------------------------------------------------
// k3 (R12): R9's verified coalesced LDS apply + XCD-matched tile remap.
// grid 2048 x 256; block g -> (b, tile) with tile/2 % 8 == g % 8, so the
// 256-row tile re-read hits the XCD L2 that k1's slab (tile/2, b) filled.
// swizzle: slot(r,w) = r*4 + (w ^ (r&3) ^ ((r>>2)&3))  (bijective per quad)
// ---------------------------------------------------------------------------
__global__ __launch_bounds__(256) void k3_apply(
    const float* __restrict__ cpu, const float* __restrict__ comb,
    float* __restrict__ out) {
  const int t = threadIdx.x;
  // XCD-matched remap (bijective over 2048):
  const int g = blockIdx.x;
  const int x = g & 7;            // XCD of this block
  const int r = g >> 3;           // 0..255
  const int b = r >> 5;           // batch 0..7
  const int m = (r & 31) >> 1;    // 0..15
  const int o = r & 1;
  const int tile = (((x + (m << 3)) << 1) | o);   // 0..255, tile/2 % 8 == x
  const size_t base4 = (((size_t)b << 8) + (size_t)tile) * 1024;

  __shared__ float4 lds4[1024];                     // 16 KB tile

  float cb[16];
  {
    const float* cp = comb + b * 16;
#pragma unroll
    for (int i = 0; i < 16; i++) cb[i] = cp[i];     // uniform -> s_load
  }

  const float4* in4 = (const float4*)cpu + base4;
  float4* out4 = (float4*)out + base4;

  const int sw = ((t >> 2) & 3) ^ ((t >> 4) & 3);   // linear-phase swizzle

  // 1. coalesced load -> swizzled LDS
#pragma unroll
  for (int i = 0; i < 4; i++) {
    const int mm = i * 256 + t;
    lds4[mm ^ sw] = in4[mm];
  }
  __syncthreads();

  // 2. own row t from LDS, compute, write back in place (rows disjoint)
  {
    const int rsw = (t & 3) ^ ((t >> 2) & 3);
    float4 q0 = lds4[t * 4 + (0 ^ rsw)];
    float4 q1 = lds4[t * 4 + (1 ^ rsw)];
    float4 q2 = lds4[t * 4 + (2 ^ rsw)];
    float4 q3 = lds4[t * 4 + (3 ^ rsw)];
    float xv[16] = {q0.x, q0.y, q0.z, q0.w, q1.x, q1.y, q1.z, q1.w,
                    q2.x, q2.y, q2.z, q2.w, q3.x, q3.y, q3.z, q3.w};
    float ov[16];
    apply_row(cb, xv, ov);
    lds4[t * 4 + (0 ^ rsw)] = make_float4(ov[0],  ov[1],  ov[2],  ov[3]);
    lds4[t * 4 + (1 ^ rsw)] = make_float4(ov[4],  ov[5],  ov[6],  ov[7]);
    lds4[t * 4 + (2 ^ rsw)] = make_float4(ov[8],  ov[9],  ov[10], ov[11]);
    lds4[t * 4 + (3 ^ rsw)] = make_float4(ov[12], ov[13], ov[14], ov[15]);
  }
  __syncthreads();

  // 3. swizzled LDS -> coalesced nontemporal store (out is never re-read)
#pragma unroll
  for (int i = 0; i < 4; i++) {
    const int mm = i * 256 + t;
    f4v v = *(const f4v*)&lds4[mm ^ sw];
    __builtin_nontemporal_store(v, (f4v*)&out4[mm]);
  }
}

extern "C" void kernel_launch(void* const* d_in, const int* in_sizes, int n_in,
                              void* d_out, int out_size, void* d_ws, size_t ws_size,
                              hipStream_t stream) {
  const float* cpu       = (const float*)d_in[0];
  const float* ctrl      = (const float*)d_in[1];
  const float* rulemem   = (const float*)d_in[2];
  const float* templates = (const float*)d_in[3];
  const float* W1        = (const float*)d_in[4];
  const float* b1        = (const float*)d_in[5];
  const float* W2        = (const float*)d_in[6];
  const float* b2        = (const float*)d_in[7];
  const float* Wr        = (const float*)d_in[8];
  const float* br        = (const float*)d_in[9];
  const float* logt      = (const float*)d_in[10];
  float* outp = (float*)d_out;

  // partial: 8*128*16 floats (64 KiB) + comb: 128 floats.
  float* partial = (float*)d_ws;
  float* comb;
  const size_t need = (size_t)(B_ * BLK_PER_B * 16 + B_ * 16) * sizeof(float);
  if (ws_size >= need) {
    comb = partial + (size_t)B_ * BLK_PER_B * 16;
  } else {
    // stage partial in the output buffer (fully consumed by k2 before k3's
    // first store; regions separated by kernel boundaries)
    partial = outp;
    comb = (float*)d_ws;
  }

  k1_reduce<<<dim3(BLK_PER_B, B_), 256, 0, stream>>>(cpu, partial);
  k2_wave<<<8, 64, 0, stream>>>(partial, ctrl, rulemem, templates, W1, b1,
                                W2, b2, Wr, br, logt, comb);
  k3_apply<<<2048, 256, 0, stream>>>(cpu, comb, outp);
}